// Round 1
// baseline (890.804 us; speedup 1.0000x reference)
//
#include <hip/hip_runtime.h>
#include <stdint.h>

#define Bb 8
#define Ss 2048
#define Dd 512

typedef _Float16 half8 __attribute__((ext_vector_type(8)));
typedef float floatx4 __attribute__((ext_vector_type(4)));

// ---------------- conversion kernels ----------------
__global__ void conv_x_kernel(const float* __restrict__ x, _Float16* __restrict__ xb) {
    int i = (blockIdx.x * 256 + threadIdx.x) * 8;
    float4 a = *(const float4*)(x + i);
    float4 b = *(const float4*)(x + i + 4);
    half8 h;
    h[0] = (_Float16)a.x; h[1] = (_Float16)a.y; h[2] = (_Float16)a.z; h[3] = (_Float16)a.w;
    h[4] = (_Float16)b.x; h[5] = (_Float16)b.y; h[6] = (_Float16)b.z; h[7] = (_Float16)b.w;
    *(half8*)(xb + i) = h;
}

// transpose + convert one 512x512 weight matrix: Wt[e][d] = W[d][e]
__global__ void conv_w_kernel(const float* __restrict__ W, _Float16* __restrict__ Wt) {
    __shared__ float t[32][33];
    int c0 = blockIdx.x * 32, r0 = blockIdx.y * 32;
    int lx = threadIdx.x & 31, ly = threadIdx.x >> 5;  // ly 0..7
#pragma unroll
    for (int i = 0; i < 32; i += 8)
        t[ly + i][lx] = W[(size_t)(r0 + ly + i) * Dd + c0 + lx];
    __syncthreads();
#pragma unroll
    for (int i = 0; i < 32; i += 8)
        Wt[(size_t)(c0 + ly + i) * Dd + r0 + lx] = (_Float16)t[lx][ly + i];
}

// ---------------- fused QKV projection GEMM ----------------
__device__ __forceinline__ void gl_lds16(const _Float16* g, _Float16* l) {
    __builtin_amdgcn_global_load_lds(
        (__attribute__((address_space(1))) void*)(g),
        (__attribute__((address_space(3))) void*)(l), 16, 0, 0);
}

__launch_bounds__(256)
__global__ void proj_kernel(const _Float16* __restrict__ xb,
                            const _Float16* __restrict__ wt,   // [3][512][512] transposed
                            const float* __restrict__ bq,
                            const float* __restrict__ bk,
                            const float* __restrict__ bv,
                            _Float16* __restrict__ qo,
                            _Float16* __restrict__ ko,
                            _Float16* __restrict__ vto) {
    __shared__ __align__(16) _Float16 At[128 * 32];
    __shared__ __align__(16) _Float16 Bt[128 * 32];
    const int pz = blockIdx.z;
    const _Float16* W = wt + (size_t)pz * Dd * Dd;
    const float* bias = (pz == 0) ? bq : ((pz == 1) ? bk : bv);
    const int tid = threadIdx.x;
    const int wv = tid >> 6, lane = tid & 63;
    const int m0 = blockIdx.x * 128, n0 = blockIdx.y * 128;
    const int li = wv * 2;
    const int srow = lane >> 2;       // 0..15
    const int scol = (lane & 3) * 8;  // 0,8,16,24
    const int wm = (wv & 1) * 64, wn = (wv >> 1) * 64;
    const int lr = lane & 15, lq = lane >> 4;
    floatx4 acc[4][4] = {};
    for (int kk = 0; kk < Dd; kk += 32) {
#pragma unroll
        for (int inst = 0; inst < 2; ++inst) {
            int r = (li + inst) * 16 + srow;
            gl_lds16(xb + (size_t)(m0 + r) * Dd + kk + scol, At + (li + inst) * 512 + lane * 8);
            gl_lds16(W + (size_t)(n0 + r) * Dd + kk + scol, Bt + (li + inst) * 512 + lane * 8);
        }
        __syncthreads();
        half8 af[4], bf[4];
#pragma unroll
        for (int mi = 0; mi < 4; ++mi)
            af[mi] = *(const half8*)&At[(wm + mi * 16 + lr) * 32 + lq * 8];
#pragma unroll
        for (int ni = 0; ni < 4; ++ni)
            bf[ni] = *(const half8*)&Bt[(wn + ni * 16 + lr) * 32 + lq * 8];
#pragma unroll
        for (int mi = 0; mi < 4; ++mi)
#pragma unroll
            for (int ni = 0; ni < 4; ++ni)
                acc[mi][ni] = __builtin_amdgcn_mfma_f32_16x16x32_f16(af[mi], bf[ni], acc[mi][ni], 0, 0, 0);
        __syncthreads();
    }
#pragma unroll
    for (int ni = 0; ni < 4; ++ni) {
        const int gn = n0 + wn + ni * 16 + lr;
        const float bb = bias[gn];
#pragma unroll
        for (int mi = 0; mi < 4; ++mi) {
#pragma unroll
            for (int r = 0; r < 4; ++r) {
                const int gm = m0 + wm + mi * 16 + lq * 4 + r;
                const float v = acc[mi][ni][r] + bb;
                if (pz == 0)      qo[(size_t)gm * Dd + gn] = (_Float16)v;
                else if (pz == 1) ko[(size_t)gm * Dd + gn] = (_Float16)v;
                else              vto[((size_t)(gm >> 11) * Dd + gn) * Ss + (gm & 2047)] = (_Float16)v;
            }
        }
    }
}

// ---------------- flash attention (static-shift softmax) ----------------
__launch_bounds__(256)
__global__ void attn_kernel(const _Float16* __restrict__ q,
                            const _Float16* __restrict__ k,
                            const _Float16* __restrict__ vt,
                            float* __restrict__ out) {
    __shared__ __align__(16) _Float16 P[2][4][640];  // ping-pong, per-wave 16x32 tile, stride 40
    const int b = blockIdx.y;
    const int wv = threadIdx.x >> 6, lane = threadIdx.x & 63;
    const int lr = lane & 15, lq = lane >> 4;
    const int qrow = blockIdx.x * 64 + wv * 16;
    const _Float16* Qb = q + (size_t)b * Ss * Dd;
    const _Float16* Kb = k + (size_t)b * Ss * Dd;
    const _Float16* Vb = vt + (size_t)b * Dd * Ss;
    half8 qf[16];
#pragma unroll
    for (int ks = 0; ks < 16; ++ks)
        qf[ks] = *(const half8*)&Qb[(size_t)(qrow + lr) * Dd + ks * 32 + lq * 8];
    floatx4 o[32] = {};
    float lp[4] = {0.f, 0.f, 0.f, 0.f};
    const float c1 = 0.044194173824159216f * 1.4426950408889634f;  // (1/sqrt(512))*log2(e)
    const float c2 = 12.0f * 1.4426950408889634f;                  // static shift
    for (int kt = 0; kt < 64; ++kt) {
        floatx4 s0 = {}, s1 = {};
        const _Float16* K0 = Kb + (size_t)(kt * 32 + lr) * Dd + lq * 8;
        const _Float16* K1 = K0 + 16 * Dd;
#pragma unroll
        for (int ks = 0; ks < 16; ++ks) {
            half8 kf0 = *(const half8*)(K0 + ks * 32);
            half8 kf1 = *(const half8*)(K1 + ks * 32);
            s0 = __builtin_amdgcn_mfma_f32_16x16x32_f16(qf[ks], kf0, s0, 0, 0, 0);
            s1 = __builtin_amdgcn_mfma_f32_16x16x32_f16(qf[ks], kf1, s1, 0, 0, 0);
        }
        _Float16* Pw = &P[kt & 1][wv][0];
#pragma unroll
        for (int i = 0; i < 4; ++i) {
            float p0 = __builtin_amdgcn_exp2f(s0[i] * c1 - c2);
            float p1 = __builtin_amdgcn_exp2f(s1[i] * c1 - c2);
            lp[i] += p0 + p1;
            Pw[(lq * 4 + i) * 40 + lr] = (_Float16)p0;
            Pw[(lq * 4 + i) * 40 + 16 + lr] = (_Float16)p1;
        }
        __syncthreads();
        half8 af = *(const half8*)&Pw[lr * 40 + lq * 8];
        const _Float16* V0 = Vb + (size_t)lr * Ss + kt * 32 + lq * 8;
#pragma unroll
        for (int nb = 0; nb < 32; ++nb) {
            half8 vf = *(const half8*)(V0 + (size_t)nb * 16 * Ss);
            o[nb] = __builtin_amdgcn_mfma_f32_16x16x32_f16(af, vf, o[nb], 0, 0, 0);
        }
    }
#pragma unroll
    for (int i = 0; i < 4; ++i) {
#pragma unroll
        for (int m = 1; m < 16; m <<= 1)
            lp[i] += __shfl_xor(lp[i], m);
        lp[i] = 1.0f / lp[i];
    }
    float* Ob = out + ((size_t)b * Ss + qrow) * Dd;
#pragma unroll
    for (int nb = 0; nb < 32; ++nb)
#pragma unroll
        for (int i = 0; i < 4; ++i)
            Ob[(lq * 4 + i) * Dd + nb * 16 + lr] = o[nb][i] * lp[i];
}

// ---------------- launch ----------------
extern "C" void kernel_launch(void* const* d_in, const int* in_sizes, int n_in,
                              void* d_out, int out_size, void* d_ws, size_t ws_size,
                              hipStream_t stream) {
    const float* x  = (const float*)d_in[0];
    const float* Wq = (const float*)d_in[1];
    const float* bq = (const float*)d_in[2];
    const float* Wk = (const float*)d_in[3];
    const float* bk = (const float*)d_in[4];
    const float* Wv = (const float*)d_in[5];
    const float* bv = (const float*)d_in[6];

    const size_t NE = (size_t)Bb * Ss * Dd;  // 8.39M elements
    _Float16* xb  = (_Float16*)d_ws;
    _Float16* qw  = xb + NE;
    _Float16* kw  = qw + NE;
    _Float16* vtw = kw + NE;
    _Float16* wt  = vtw + NE;  // 3 * 512*512

    conv_x_kernel<<<dim3((unsigned)(NE / 2048)), 256, 0, stream>>>(x, xb);
    conv_w_kernel<<<dim3(16, 16), 256, 0, stream>>>(Wq, wt);
    conv_w_kernel<<<dim3(16, 16), 256, 0, stream>>>(Wk, wt + Dd * Dd);
    conv_w_kernel<<<dim3(16, 16), 256, 0, stream>>>(Wv, wt + 2 * Dd * Dd);
    proj_kernel<<<dim3(128, 4, 3), 256, 0, stream>>>(xb, wt, bq, bk, bv, qw, kw, vtw);
    attn_kernel<<<dim3(32, 8), 256, 0, stream>>>(qw, kw, vtw, (float*)d_out);
}

// Round 2
// 839.425 us; speedup vs baseline: 1.0612x; 1.0612x over previous
//
#include <hip/hip_runtime.h>
#include <stdint.h>

#define Bb 8
#define Ss 2048
#define Dd 512

typedef _Float16 half8 __attribute__((ext_vector_type(8)));
typedef float floatx4 __attribute__((ext_vector_type(4)));

// ---------------- conversion kernels ----------------
__global__ void conv_x_kernel(const float* __restrict__ x, _Float16* __restrict__ xb) {
    int i = (blockIdx.x * 256 + threadIdx.x) * 8;
    float4 a = *(const float4*)(x + i);
    float4 b = *(const float4*)(x + i + 4);
    half8 h;
    h[0] = (_Float16)a.x; h[1] = (_Float16)a.y; h[2] = (_Float16)a.z; h[3] = (_Float16)a.w;
    h[4] = (_Float16)b.x; h[5] = (_Float16)b.y; h[6] = (_Float16)b.z; h[7] = (_Float16)b.w;
    *(half8*)(xb + i) = h;
}

// transpose + convert one 512x512 weight matrix: Wt[e][d] = W[d][e]
__global__ void conv_w_kernel(const float* __restrict__ W, _Float16* __restrict__ Wt) {
    __shared__ float t[32][33];
    int c0 = blockIdx.x * 32, r0 = blockIdx.y * 32;
    int lx = threadIdx.x & 31, ly = threadIdx.x >> 5;  // ly 0..7
#pragma unroll
    for (int i = 0; i < 32; i += 8)
        t[ly + i][lx] = W[(size_t)(r0 + ly + i) * Dd + c0 + lx];
    __syncthreads();
#pragma unroll
    for (int i = 0; i < 32; i += 8)
        Wt[(size_t)(c0 + ly + i) * Dd + r0 + lx] = (_Float16)t[lx][ly + i];
}

// ---------------- fused QKV projection GEMM ----------------
__device__ __forceinline__ void gl_lds16(const _Float16* g, _Float16* l) {
    __builtin_amdgcn_global_load_lds(
        (__attribute__((address_space(1))) void*)(g),
        (__attribute__((address_space(3))) void*)(l), 16, 0, 0);
}

__launch_bounds__(256)
__global__ void proj_kernel(const _Float16* __restrict__ xb,
                            const _Float16* __restrict__ wt,   // [3][512][512] transposed
                            const float* __restrict__ bq,
                            const float* __restrict__ bk,
                            const float* __restrict__ bv,
                            _Float16* __restrict__ qo,
                            _Float16* __restrict__ ko,
                            _Float16* __restrict__ vto) {
    __shared__ __align__(16) _Float16 At[128 * 32];
    __shared__ __align__(16) _Float16 Bt[128 * 32];
    const int pz = blockIdx.z;
    const _Float16* W = wt + (size_t)pz * Dd * Dd;
    const float* bias = (pz == 0) ? bq : ((pz == 1) ? bk : bv);
    const int tid = threadIdx.x;
    const int wv = tid >> 6, lane = tid & 63;
    const int m0 = blockIdx.x * 128, n0 = blockIdx.y * 128;
    const int li = wv * 2;
    const int srow = lane >> 2;       // 0..15
    const int scol = (lane & 3) * 8;  // 0,8,16,24
    const int wm = (wv & 1) * 64, wn = (wv >> 1) * 64;
    const int lr = lane & 15, lq = lane >> 4;
    floatx4 acc[4][4] = {};
    for (int kk = 0; kk < Dd; kk += 32) {
#pragma unroll
        for (int inst = 0; inst < 2; ++inst) {
            int r = (li + inst) * 16 + srow;
            gl_lds16(xb + (size_t)(m0 + r) * Dd + kk + scol, At + (li + inst) * 512 + lane * 8);
            gl_lds16(W + (size_t)(n0 + r) * Dd + kk + scol, Bt + (li + inst) * 512 + lane * 8);
        }
        __syncthreads();
        half8 af[4], bf[4];
#pragma unroll
        for (int mi = 0; mi < 4; ++mi)
            af[mi] = *(const half8*)&At[(wm + mi * 16 + lr) * 32 + lq * 8];
#pragma unroll
        for (int ni = 0; ni < 4; ++ni)
            bf[ni] = *(const half8*)&Bt[(wn + ni * 16 + lr) * 32 + lq * 8];
#pragma unroll
        for (int mi = 0; mi < 4; ++mi)
#pragma unroll
            for (int ni = 0; ni < 4; ++ni)
                acc[mi][ni] = __builtin_amdgcn_mfma_f32_16x16x32_f16(af[mi], bf[ni], acc[mi][ni], 0, 0, 0);
        __syncthreads();
    }
#pragma unroll
    for (int ni = 0; ni < 4; ++ni) {
        const int gn = n0 + wn + ni * 16 + lr;
        const float bb = bias[gn];
#pragma unroll
        for (int mi = 0; mi < 4; ++mi) {
#pragma unroll
            for (int r = 0; r < 4; ++r) {
                const int gm = m0 + wm + mi * 16 + lq * 4 + r;
                const float v = acc[mi][ni][r] + bb;
                if (pz == 0)      qo[(size_t)gm * Dd + gn] = (_Float16)v;
                else if (pz == 1) ko[(size_t)gm * Dd + gn] = (_Float16)v;
                else              vto[((size_t)(gm >> 11) * Dd + gn) * Ss + (gm & 2047)] = (_Float16)v;
            }
        }
    }
}

// ---------------- flash attention (static-shift softmax) ----------------
// Grid: (S/64, B, 2). blockIdx.z selects a 256-col half of D for the PV/output
// side; scores are recomputed per half (MFMA was at 3.6% util — parallelism
// matters more). 4 waves/block, each wave = 16 q-rows, NO in-loop barrier:
// the P transpose tile is wave-private LDS.
__launch_bounds__(256)
__global__ void attn_kernel(const _Float16* __restrict__ q,
                            const _Float16* __restrict__ k,
                            const _Float16* __restrict__ vt,
                            float* __restrict__ out) {
    __shared__ __align__(16) _Float16 P[4][16 * 40];  // per-wave 16x32 tile, stride 40
    const int b = blockIdx.y;
    const int zoff = blockIdx.z * 16;  // nb offset (16 nb-blocks of 16 cols per half)
    const int wv = threadIdx.x >> 6, lane = threadIdx.x & 63;
    const int lr = lane & 15, lq = lane >> 4;
    const int qrow = blockIdx.x * 64 + wv * 16;
    const _Float16* Qb = q + (size_t)b * Ss * Dd;
    const _Float16* Kb = k + (size_t)b * Ss * Dd;
    const _Float16* Vb = vt + (size_t)b * Dd * Ss;
    half8 qf[16];
#pragma unroll
    for (int ks = 0; ks < 16; ++ks)
        qf[ks] = *(const half8*)&Qb[(size_t)(qrow + lr) * Dd + ks * 32 + lq * 8];
    floatx4 o[16] = {};
    float lp[4] = {0.f, 0.f, 0.f, 0.f};
    const float c1 = 0.044194173824159216f * 1.4426950408889634f;  // (1/sqrt(512))*log2(e)
    const float c2 = 12.0f * 1.4426950408889634f;                  // static shift
    for (int kt = 0; kt < 64; ++kt) {
        // ---- scores: 4 independent 8-deep MFMA chains ----
        floatx4 s0a = {}, s0b = {}, s1a = {}, s1b = {};
        const _Float16* K0 = Kb + (size_t)(kt * 32 + lr) * Dd + lq * 8;
        const _Float16* K1 = K0 + 16 * Dd;
#pragma unroll
        for (int ks = 0; ks < 16; ks += 2) {
            half8 kf0a = *(const half8*)(K0 + ks * 32);
            half8 kf0b = *(const half8*)(K0 + ks * 32 + 32);
            half8 kf1a = *(const half8*)(K1 + ks * 32);
            half8 kf1b = *(const half8*)(K1 + ks * 32 + 32);
            s0a = __builtin_amdgcn_mfma_f32_16x16x32_f16(qf[ks], kf0a, s0a, 0, 0, 0);
            s0b = __builtin_amdgcn_mfma_f32_16x16x32_f16(qf[ks + 1], kf0b, s0b, 0, 0, 0);
            s1a = __builtin_amdgcn_mfma_f32_16x16x32_f16(qf[ks], kf1a, s1a, 0, 0, 0);
            s1b = __builtin_amdgcn_mfma_f32_16x16x32_f16(qf[ks + 1], kf1b, s1b, 0, 0, 0);
        }
        _Float16* Pw = &P[wv][0];
#pragma unroll
        for (int i = 0; i < 4; ++i) {
            float p0 = __builtin_amdgcn_exp2f((s0a[i] + s0b[i]) * c1 - c2);
            float p1 = __builtin_amdgcn_exp2f((s1a[i] + s1b[i]) * c1 - c2);
            lp[i] += p0 + p1;
            Pw[(lq * 4 + i) * 40 + lr] = (_Float16)p0;
            Pw[(lq * 4 + i) * 40 + 16 + lr] = (_Float16)p1;
        }
        // wave-private LDS round-trip: compiler inserts lgkmcnt wait, no barrier
        half8 af = *(const half8*)&Pw[lr * 40 + lq * 8];
        const _Float16* V0 = Vb + ((size_t)zoff * 16 + lr) * Ss + kt * 32 + lq * 8;
#pragma unroll
        for (int nb = 0; nb < 16; ++nb) {
            half8 vf = *(const half8*)(V0 + (size_t)nb * 16 * Ss);
            o[nb] = __builtin_amdgcn_mfma_f32_16x16x32_f16(af, vf, o[nb], 0, 0, 0);
        }
    }
#pragma unroll
    for (int i = 0; i < 4; ++i) {
#pragma unroll
        for (int m = 1; m < 16; m <<= 1)
            lp[i] += __shfl_xor(lp[i], m);
        lp[i] = 1.0f / lp[i];
    }
    float* Ob = out + ((size_t)b * Ss + qrow) * Dd;
#pragma unroll
    for (int nb = 0; nb < 16; ++nb)
#pragma unroll
        for (int i = 0; i < 4; ++i)
            Ob[(lq * 4 + i) * Dd + (zoff + nb) * 16 + lr] = o[nb][i] * lp[i];
}

// ---------------- launch ----------------
extern "C" void kernel_launch(void* const* d_in, const int* in_sizes, int n_in,
                              void* d_out, int out_size, void* d_ws, size_t ws_size,
                              hipStream_t stream) {
    const float* x  = (const float*)d_in[0];
    const float* Wq = (const float*)d_in[1];
    const float* bq = (const float*)d_in[2];
    const float* Wk = (const float*)d_in[3];
    const float* bk = (const float*)d_in[4];
    const float* Wv = (const float*)d_in[5];
    const float* bv = (const float*)d_in[6];

    const size_t NE = (size_t)Bb * Ss * Dd;  // 8.39M elements
    _Float16* xb  = (_Float16*)d_ws;
    _Float16* qw  = xb + NE;
    _Float16* kw  = qw + NE;
    _Float16* vtw = kw + NE;
    _Float16* wt  = vtw + NE;  // 3 * 512*512

    conv_x_kernel<<<dim3((unsigned)(NE / 2048)), 256, 0, stream>>>(x, xb);
    conv_w_kernel<<<dim3(16, 16), 256, 0, stream>>>(Wq, wt);
    conv_w_kernel<<<dim3(16, 16), 256, 0, stream>>>(Wk, wt + Dd * Dd);
    conv_w_kernel<<<dim3(16, 16), 256, 0, stream>>>(Wv, wt + 2 * Dd * Dd);
    proj_kernel<<<dim3(128, 4, 3), 256, 0, stream>>>(xb, wt, bq, bk, bv, qw, kw, vtw);
    attn_kernel<<<dim3(32, 8, 2), 256, 0, stream>>>(qw, kw, vtw, (float*)d_out);
}

// Round 3
// 337.924 us; speedup vs baseline: 2.6361x; 2.4841x over previous
//
#include <hip/hip_runtime.h>
#include <stdint.h>

#define Bb 8
#define Ss 2048
#define Dd 512

typedef _Float16 half8 __attribute__((ext_vector_type(8)));
typedef float floatx4 __attribute__((ext_vector_type(4)));

// ---------------- conversion kernels ----------------
__global__ void conv_x_kernel(const float* __restrict__ x, _Float16* __restrict__ xb) {
    int i = (blockIdx.x * 256 + threadIdx.x) * 8;
    float4 a = *(const float4*)(x + i);
    float4 b = *(const float4*)(x + i + 4);
    half8 h;
    h[0] = (_Float16)a.x; h[1] = (_Float16)a.y; h[2] = (_Float16)a.z; h[3] = (_Float16)a.w;
    h[4] = (_Float16)b.x; h[5] = (_Float16)b.y; h[6] = (_Float16)b.z; h[7] = (_Float16)b.w;
    *(half8*)(xb + i) = h;
}

// transpose + convert one 512x512 weight matrix: Wt[e][d] = W[d][e]
__global__ void conv_w_kernel(const float* __restrict__ W, _Float16* __restrict__ Wt) {
    __shared__ float t[32][33];
    int c0 = blockIdx.x * 32, r0 = blockIdx.y * 32;
    int lx = threadIdx.x & 31, ly = threadIdx.x >> 5;  // ly 0..7
#pragma unroll
    for (int i = 0; i < 32; i += 8)
        t[ly + i][lx] = W[(size_t)(r0 + ly + i) * Dd + c0 + lx];
    __syncthreads();
#pragma unroll
    for (int i = 0; i < 32; i += 8)
        Wt[(size_t)(c0 + ly + i) * Dd + r0 + lx] = (_Float16)t[lx][ly + i];
}

// ---------------- fused QKV projection GEMM ----------------
__device__ __forceinline__ void gl_lds16(const _Float16* g, _Float16* l) {
    __builtin_amdgcn_global_load_lds(
        (__attribute__((address_space(1))) void*)(g),
        (__attribute__((address_space(3))) void*)(l), 16, 0, 0);
}

__launch_bounds__(256)
__global__ void proj_kernel(const _Float16* __restrict__ xb,
                            const _Float16* __restrict__ wt,   // [3][512][512] transposed
                            const float* __restrict__ bq,
                            const float* __restrict__ bk,
                            const float* __restrict__ bv,
                            _Float16* __restrict__ qo,
                            _Float16* __restrict__ ko,
                            _Float16* __restrict__ vto) {
    __shared__ __align__(16) _Float16 At[128 * 32];
    __shared__ __align__(16) _Float16 Bt[128 * 32];
    const int pz = blockIdx.z;
    const _Float16* W = wt + (size_t)pz * Dd * Dd;
    const float* bias = (pz == 0) ? bq : ((pz == 1) ? bk : bv);
    const int tid = threadIdx.x;
    const int wv = tid >> 6, lane = tid & 63;
    const int m0 = blockIdx.x * 128, n0 = blockIdx.y * 128;
    const int li = wv * 2;
    const int srow = lane >> 2;       // 0..15
    const int scol = (lane & 3) * 8;  // 0,8,16,24
    const int wm = (wv & 1) * 64, wn = (wv >> 1) * 64;
    const int lr = lane & 15, lq = lane >> 4;
    floatx4 acc[4][4] = {};
    for (int kk = 0; kk < Dd; kk += 32) {
#pragma unroll
        for (int inst = 0; inst < 2; ++inst) {
            int r = (li + inst) * 16 + srow;
            gl_lds16(xb + (size_t)(m0 + r) * Dd + kk + scol, At + (li + inst) * 512 + lane * 8);
            gl_lds16(W + (size_t)(n0 + r) * Dd + kk + scol, Bt + (li + inst) * 512 + lane * 8);
        }
        __syncthreads();
        half8 af[4], bf[4];
#pragma unroll
        for (int mi = 0; mi < 4; ++mi)
            af[mi] = *(const half8*)&At[(wm + mi * 16 + lr) * 32 + lq * 8];
#pragma unroll
        for (int ni = 0; ni < 4; ++ni)
            bf[ni] = *(const half8*)&Bt[(wn + ni * 16 + lr) * 32 + lq * 8];
#pragma unroll
        for (int mi = 0; mi < 4; ++mi)
#pragma unroll
            for (int ni = 0; ni < 4; ++ni)
                acc[mi][ni] = __builtin_amdgcn_mfma_f32_16x16x32_f16(af[mi], bf[ni], acc[mi][ni], 0, 0, 0);
        __syncthreads();
    }
#pragma unroll
    for (int ni = 0; ni < 4; ++ni) {
        const int gn = n0 + wn + ni * 16 + lr;
        const float bb = bias[gn];
#pragma unroll
        for (int mi = 0; mi < 4; ++mi) {
#pragma unroll
            for (int r = 0; r < 4; ++r) {
                const int gm = m0 + wm + mi * 16 + lq * 4 + r;
                const float v = acc[mi][ni][r] + bb;
                if (pz == 0)      qo[(size_t)gm * Dd + gn] = (_Float16)v;
                else if (pz == 1) ko[(size_t)gm * Dd + gn] = (_Float16)v;
                else              vto[((size_t)(gm >> 11) * Dd + gn) * Ss + (gm & 2047)] = (_Float16)v;
            }
        }
    }
}

// ---------------- flash attention, LDS-staged K/V ----------------
// Grid (S/64, B, 2). Block = 4 waves, Q-tile 64 rows (16/wave), z = 256-col
// half of D. Per kt: cooperatively stage K-tile (32x512, 32KB) + V^T-half
// (256x32, 16KB) into LDS via global_load_lds(16B), barrier, MFMA from LDS.
// K-tile shared by all 4 waves (was 4x redundant global reads in R2).
// __launch_bounds__(256,3): 12 waves/CU; LDS 52.5KB -> 3 blocks/CU.
__launch_bounds__(256, 3)
__global__ void attn_kernel(const _Float16* __restrict__ q,
                            const _Float16* __restrict__ k,
                            const _Float16* __restrict__ vt,
                            float* __restrict__ out) {
    __shared__ __align__(16) _Float16 Klds[32 * 512];   // [bi=g*16+s][row*32+chunk*8]
    __shared__ __align__(16) _Float16 Vlds[256 * 32];   // [drow][32 k]
    __shared__ __align__(16) _Float16 P[4][16 * 36];    // per-wave P tile, stride 36
    const int b = blockIdx.y;
    const int z = blockIdx.z;
    const int wv = threadIdx.x >> 6, lane = threadIdx.x & 63;
    const int lr = lane & 15, lq = lane >> 4;
    const int qrow = blockIdx.x * 64 + wv * 16;
    const _Float16* Qb = q + (size_t)b * Ss * Dd;
    const _Float16* Vbz = vt + (size_t)b * Dd * Ss + (size_t)z * 256 * Ss;

    // Q fragments, register-resident for the whole kernel (64 VGPR)
    half8 qf[16];
#pragma unroll
    for (int s = 0; s < 16; ++s)
        qf[s] = *(const half8*)&Qb[(size_t)(qrow + lr) * Dd + s * 32 + lq * 8];

    // staging source pointers (advance per kt)
    // K: wave wv stages bi = wv*8+j, j=0..7; bi=g*16+s -> g=wv>>1, s=(wv&1)*8+j
    const int sg = wv >> 1;
    const int s0 = (wv & 1) * 8;
    const _Float16* kptr = k + (size_t)b * Ss * Dd
                         + (size_t)(sg * 16 + (lane >> 2)) * Dd + s0 * 32 + (lane & 3) * 8;
    // V: wave wv stages i = wv*4+j, j=0..3; drow = i*16 + lane>>2
    const _Float16* vptr = Vbz + (size_t)(wv * 64 + (lane >> 2)) * Ss + (lane & 3) * 8;
    _Float16* kdst = Klds + (sg * 16 + s0) * 512 + lane * 8;
    _Float16* vdst = Vlds + wv * 4 * 512 + lane * 8;

    floatx4 o[16] = {};
    float lp[4] = {0.f, 0.f, 0.f, 0.f};
    const float c1 = 0.044194173824159216f * 1.4426950408889634f;  // (1/sqrt(512))*log2(e)
    const float c2 = 12.0f * 1.4426950408889634f;                  // static shift
    _Float16* Pw = &P[wv][0];

    for (int kt = 0; kt < 64; ++kt) {
        // ---- stage K (8 insts/thread) + V (4 insts/thread) ----
#pragma unroll
        for (int j = 0; j < 8; ++j)
            gl_lds16(kptr + j * 32, kdst + j * 512);
#pragma unroll
        for (int j = 0; j < 4; ++j)
            gl_lds16(vptr + (size_t)j * 16 * Ss, vdst + j * 512);
        kptr += 32 * Dd;
        vptr += 32;
        __syncthreads();  // drains vmcnt: staging visible to all waves

        // ---- QK^T: 4 independent 8-deep chains ----
        floatx4 s0a = {}, s0b = {}, s1a = {}, s1b = {};
#pragma unroll
        for (int s = 0; s < 16; s += 2) {
            half8 kf0a = *(const half8*)&Klds[(0 * 16 + s) * 512 + lr * 32 + lq * 8];
            half8 kf0b = *(const half8*)&Klds[(0 * 16 + s + 1) * 512 + lr * 32 + lq * 8];
            half8 kf1a = *(const half8*)&Klds[(1 * 16 + s) * 512 + lr * 32 + lq * 8];
            half8 kf1b = *(const half8*)&Klds[(1 * 16 + s + 1) * 512 + lr * 32 + lq * 8];
            s0a = __builtin_amdgcn_mfma_f32_16x16x32_f16(qf[s], kf0a, s0a, 0, 0, 0);
            s0b = __builtin_amdgcn_mfma_f32_16x16x32_f16(qf[s + 1], kf0b, s0b, 0, 0, 0);
            s1a = __builtin_amdgcn_mfma_f32_16x16x32_f16(qf[s], kf1a, s1a, 0, 0, 0);
            s1b = __builtin_amdgcn_mfma_f32_16x16x32_f16(qf[s + 1], kf1b, s1b, 0, 0, 0);
        }

        // ---- softmax (static shift) + P transpose via wave-private LDS ----
#pragma unroll
        for (int i = 0; i < 4; ++i) {
            float p0 = __builtin_amdgcn_exp2f((s0a[i] + s0b[i]) * c1 - c2);
            float p1 = __builtin_amdgcn_exp2f((s1a[i] + s1b[i]) * c1 - c2);
            lp[i] += p0 + p1;
            Pw[(lq * 4 + i) * 36 + lr] = (_Float16)p0;
            Pw[(lq * 4 + i) * 36 + 16 + lr] = (_Float16)p1;
        }
        half8 af = *(const half8*)&Pw[lr * 36 + lq * 8];  // lgkmcnt wait, no barrier

        // ---- PV: 16 independent accumulator chains ----
#pragma unroll
        for (int nb = 0; nb < 16; ++nb) {
            half8 vf = *(const half8*)&Vlds[(nb * 16 + lr) * 32 + lq * 8];
            o[nb] = __builtin_amdgcn_mfma_f32_16x16x32_f16(af, vf, o[nb], 0, 0, 0);
        }
        __syncthreads();  // protect staging buffers before next overwrite
    }

#pragma unroll
    for (int i = 0; i < 4; ++i) {
#pragma unroll
        for (int m = 1; m < 16; m <<= 1)
            lp[i] += __shfl_xor(lp[i], m);
        lp[i] = 1.0f / lp[i];
    }
    float* Ob = out + ((size_t)b * Ss + qrow) * Dd + z * 256;
#pragma unroll
    for (int nb = 0; nb < 16; ++nb)
#pragma unroll
        for (int i = 0; i < 4; ++i)
            Ob[(lq * 4 + i) * Dd + nb * 16 + lr] = o[nb][i] * lp[i];
}

// ---------------- launch ----------------
extern "C" void kernel_launch(void* const* d_in, const int* in_sizes, int n_in,
                              void* d_out, int out_size, void* d_ws, size_t ws_size,
                              hipStream_t stream) {
    const float* x  = (const float*)d_in[0];
    const float* Wq = (const float*)d_in[1];
    const float* bq = (const float*)d_in[2];
    const float* Wk = (const float*)d_in[3];
    const float* bk = (const float*)d_in[4];
    const float* Wv = (const float*)d_in[5];
    const float* bv = (const float*)d_in[6];

    const size_t NE = (size_t)Bb * Ss * Dd;  // 8.39M elements
    _Float16* xb  = (_Float16*)d_ws;
    _Float16* qw  = xb + NE;
    _Float16* kw  = qw + NE;
    _Float16* vtw = kw + NE;
    _Float16* wt  = vtw + NE;  // 3 * 512*512

    conv_x_kernel<<<dim3((unsigned)(NE / 2048)), 256, 0, stream>>>(x, xb);
    conv_w_kernel<<<dim3(16, 16), 256, 0, stream>>>(Wq, wt);
    conv_w_kernel<<<dim3(16, 16), 256, 0, stream>>>(Wk, wt + Dd * Dd);
    conv_w_kernel<<<dim3(16, 16), 256, 0, stream>>>(Wv, wt + 2 * Dd * Dd);
    proj_kernel<<<dim3(128, 4, 3), 256, 0, stream>>>(xb, wt, bq, bk, bv, qw, kw, vtw);
    attn_kernel<<<dim3(32, 8, 2), 256, 0, stream>>>(qw, kw, vtw, (float*)d_out);
}

// Round 4
// 262.095 us; speedup vs baseline: 3.3988x; 1.2893x over previous
//
#include <hip/hip_runtime.h>
#include <stdint.h>

#define Bb 8
#define Ss 2048
#define Dd 512

typedef _Float16 half8 __attribute__((ext_vector_type(8)));
typedef float floatx4 __attribute__((ext_vector_type(4)));

// ---------------- conversion kernels ----------------
__global__ void conv_x_kernel(const float* __restrict__ x, _Float16* __restrict__ xb) {
    int i = (blockIdx.x * 256 + threadIdx.x) * 8;
    float4 a = *(const float4*)(x + i);
    float4 b = *(const float4*)(x + i + 4);
    half8 h;
    h[0] = (_Float16)a.x; h[1] = (_Float16)a.y; h[2] = (_Float16)a.z; h[3] = (_Float16)a.w;
    h[4] = (_Float16)b.x; h[5] = (_Float16)b.y; h[6] = (_Float16)b.z; h[7] = (_Float16)b.w;
    *(half8*)(xb + i) = h;
}

// transpose + convert one 512x512 weight matrix: Wt[e][d] = W[d][e]
__global__ void conv_w_kernel(const float* __restrict__ W, _Float16* __restrict__ Wt) {
    __shared__ float t[32][33];
    int c0 = blockIdx.x * 32, r0 = blockIdx.y * 32;
    int lx = threadIdx.x & 31, ly = threadIdx.x >> 5;  // ly 0..7
#pragma unroll
    for (int i = 0; i < 32; i += 8)
        t[ly + i][lx] = W[(size_t)(r0 + ly + i) * Dd + c0 + lx];
    __syncthreads();
#pragma unroll
    for (int i = 0; i < 32; i += 8)
        Wt[(size_t)(c0 + ly + i) * Dd + r0 + lx] = (_Float16)t[lx][ly + i];
}

// ---------------- fused QKV projection GEMM ----------------
__device__ __forceinline__ void gl_lds16(const _Float16* g, _Float16* l) {
    __builtin_amdgcn_global_load_lds(
        (__attribute__((address_space(1))) void*)(g),
        (__attribute__((address_space(3))) void*)(l), 16, 0, 0);
}

__launch_bounds__(256)
__global__ void proj_kernel(const _Float16* __restrict__ xb,
                            const _Float16* __restrict__ wt,   // [3][512][512] transposed
                            const float* __restrict__ bq,
                            const float* __restrict__ bk,
                            const float* __restrict__ bv,
                            _Float16* __restrict__ qo,
                            _Float16* __restrict__ ko,
                            _Float16* __restrict__ vto) {
    __shared__ __align__(16) _Float16 At[128 * 32];
    __shared__ __align__(16) _Float16 Bt[128 * 32];
    __shared__ __align__(16) _Float16 R[128 * 136];  // repack tile (stride 136: 16B-aligned rows)
    const int pz = blockIdx.z;
    const _Float16* W = wt + (size_t)pz * Dd * Dd;
    const float* bias = (pz == 0) ? bq : ((pz == 1) ? bk : bv);
    const int tid = threadIdx.x;
    const int wv = tid >> 6, lane = tid & 63;
    const int m0 = blockIdx.x * 128, n0 = blockIdx.y * 128;
    const int li = wv * 2;
    const int srow = lane >> 2;       // 0..15
    const int scol = (lane & 3) * 8;  // 0,8,16,24
    const int wm = (wv & 1) * 64, wn = (wv >> 1) * 64;
    const int lr = lane & 15, lq = lane >> 4;
    floatx4 acc[4][4] = {};
    for (int kk = 0; kk < Dd; kk += 32) {
#pragma unroll
        for (int inst = 0; inst < 2; ++inst) {
            int r = (li + inst) * 16 + srow;
            gl_lds16(xb + (size_t)(m0 + r) * Dd + kk + scol, At + (li + inst) * 512 + lane * 8);
            gl_lds16(W + (size_t)(n0 + r) * Dd + kk + scol, Bt + (li + inst) * 512 + lane * 8);
        }
        __syncthreads();
        half8 af[4], bf[4];
#pragma unroll
        for (int mi = 0; mi < 4; ++mi)
            af[mi] = *(const half8*)&At[(wm + mi * 16 + lr) * 32 + lq * 8];
#pragma unroll
        for (int ni = 0; ni < 4; ++ni)
            bf[ni] = *(const half8*)&Bt[(wn + ni * 16 + lr) * 32 + lq * 8];
#pragma unroll
        for (int mi = 0; mi < 4; ++mi)
#pragma unroll
            for (int ni = 0; ni < 4; ++ni)
                acc[mi][ni] = __builtin_amdgcn_mfma_f32_16x16x32_f16(af[mi], bf[ni], acc[mi][ni], 0, 0, 0);
        __syncthreads();
    }
    // ---- epilogue: bias + repack through LDS, then coalesced half8 stores ----
#pragma unroll
    for (int ni = 0; ni < 4; ++ni) {
        const int gn_l = wn + ni * 16 + lr;
        const float bb = bias[n0 + gn_l];
#pragma unroll
        for (int mi = 0; mi < 4; ++mi) {
#pragma unroll
            for (int rr = 0; rr < 4; ++rr) {
                const int gm_l = wm + mi * 16 + lq * 4 + rr;
                const float v = acc[mi][ni][rr] + bb;
                if (pz == 2) R[gn_l * 136 + gm_l] = (_Float16)v;   // v: transposed layout
                else         R[gm_l * 136 + gn_l] = (_Float16)v;   // q,k: row-major
            }
        }
    }
    __syncthreads();
    const int row = tid >> 1, hf = tid & 1;
    _Float16* dst;
    if (pz == 0)      dst = qo + (size_t)(m0 + row) * Dd + n0 + hf * 64;
    else if (pz == 1) dst = ko + (size_t)(m0 + row) * Dd + n0 + hf * 64;
    else              dst = vto + ((size_t)(m0 >> 11) * Dd + n0 + row) * Ss + (m0 & 2047) + hf * 64;
#pragma unroll
    for (int j = 0; j < 8; ++j)
        *(half8*)(dst + j * 8) = *(const half8*)&R[row * 136 + hf * 64 + j * 8];
}

// ---------------- flash attention (static-shift softmax), role-split waves ----------------
// Grid (S/64, B), block 512 threads = 8 waves, 64 Q-rows/block, K-tile 64, full D.
// Score phase: wave roles (r = wv>>1: 4 row-groups of 16, c = wv&1: 2 col-groups of 32)
//   -> each wave reads only half the K-tile from LDS (K-read amortization 2x).
// PV phase: wave roles d = wv: 8 D-col groups of 64 -> V-frags amortized over 4 row-tiles.
// LDS ~143 KB -> 1 block/CU, 8 waves = 2 waves/SIMD.
__launch_bounds__(512, 2)
__global__ void attn_kernel(const _Float16* __restrict__ q,
                            const _Float16* __restrict__ k,
                            const _Float16* __restrict__ vt,
                            float* __restrict__ out) {
    __shared__ __align__(16) _Float16 Klds[64 * 520];   // [key-col][512 d + 8 pad]
    __shared__ __align__(16) _Float16 Vlds[64 * 520];   // 64 groups: [8 d-rows x 64 keys + 8 pad]
    __shared__ __align__(16) _Float16 P[64 * 72];       // [row][64 cols + 8 pad]
    __shared__ float lsum[2][64];
    const int b = blockIdx.y;
    const int tid = threadIdx.x;
    const int wv = tid >> 6, lane = tid & 63;
    const int lr = lane & 15, lq = lane >> 4;
    const int r = wv >> 1, c = wv & 1;   // score roles
    const int d = wv;                    // PV role
    const int qrow0 = blockIdx.x * 64;
    const _Float16* Qb = q + (size_t)b * Ss * Dd;
    const _Float16* Kb = k + (size_t)b * Ss * Dd;
    const _Float16* Vb = vt + (size_t)b * Dd * Ss;

    // Q fragments for this wave's 16 score rows (64 VGPR, kernel-resident)
    half8 qf[16];
#pragma unroll
    for (int s = 0; s < 16; ++s)
        qf[s] = *(const half8*)&Qb[(size_t)(qrow0 + r * 16 + lr) * Dd + s * 32 + lq * 8];

    floatx4 o[4][4] = {};
    float lp[4] = {0.f, 0.f, 0.f, 0.f};
    const float c1 = 0.044194173824159216f * 1.4426950408889634f;  // (1/sqrt(512))*log2(e)
    const float c2 = 12.0f * 1.4426950408889634f;                  // static shift

    for (int kt = 0; kt < 32; ++kt) {
        // ---- cooperative staging: K 64x512 (64 KB) + V^T 512x64 (64 KB) ----
#pragma unroll
        for (int j = 0; j < 8; ++j) {
            const int kc = wv * 8 + j;
            gl_lds16(Kb + (size_t)(kt * 64 + kc) * Dd + lane * 8, Klds + kc * 520 + lane * 8);
        }
#pragma unroll
        for (int j = 0; j < 8; ++j) {
            const int g = wv * 8 + j;   // d-octet group
            gl_lds16(Vb + (size_t)(8 * g + (lane >> 3)) * Ss + kt * 64 + (lane & 7) * 8,
                     Vlds + g * 520 + lane * 8);
        }
        __syncthreads();

        // ---- scores: 16 rows x 32 cols per wave, 4 independent chains ----
        floatx4 s[2][2] = {};
#pragma unroll
        for (int kk = 0; kk < 16; ++kk) {
#pragma unroll
            for (int ct = 0; ct < 2; ++ct) {
                half8 kf = *(const half8*)&Klds[(c * 32 + ct * 16 + lr) * 520 + kk * 32 + lq * 8];
                s[ct][kk & 1] = __builtin_amdgcn_mfma_f32_16x16x32_f16(qf[kk], kf, s[ct][kk & 1], 0, 0, 0);
            }
        }
        // ---- softmax (static shift) + write P ----
#pragma unroll
        for (int ct = 0; ct < 2; ++ct)
#pragma unroll
            for (int i = 0; i < 4; ++i) {
                float p = __builtin_amdgcn_exp2f((s[ct][0][i] + s[ct][1][i]) * c1 - c2);
                lp[i] += p;
                P[(r * 16 + lq * 4 + i) * 72 + c * 32 + ct * 16 + lr] = (_Float16)p;
            }
        __syncthreads();

        // ---- PV: o(64 rows x this wave's 64 D-cols) += P(64x64) * V(64x64) ----
#pragma unroll
        for (int kk2 = 0; kk2 < 2; ++kk2) {
            half8 af[4];
#pragma unroll
            for (int m = 0; m < 4; ++m)
                af[m] = *(const half8*)&P[(m * 16 + lr) * 72 + kk2 * 32 + lq * 8];
#pragma unroll
            for (int nt = 0; nt < 4; ++nt) {
                const int dcol = d * 64 + nt * 16 + lr;
                half8 vf = *(const half8*)&Vlds[(dcol >> 3) * 520 + (dcol & 7) * 64 + kk2 * 32 + lq * 8];
#pragma unroll
                for (int m = 0; m < 4; ++m)
                    o[m][nt] = __builtin_amdgcn_mfma_f32_16x16x32_f16(af[m], vf, o[m][nt], 0, 0, 0);
            }
        }
        __syncthreads();  // protect Klds/Vlds/P before next staging
    }

    // ---- row-sum combine across the two col-groups ----
#pragma unroll
    for (int i = 0; i < 4; ++i) {
#pragma unroll
        for (int m = 1; m < 16; m <<= 1)
            lp[i] += __shfl_xor(lp[i], m);
    }
    if (lr == 0) {
#pragma unroll
        for (int i = 0; i < 4; ++i)
            lsum[c][r * 16 + lq * 4 + i] = lp[i];
    }
    __syncthreads();

    // ---- epilogue: wave d writes its 64 D-cols for all 64 rows ----
    float* Ob = out + ((size_t)b * Ss + qrow0) * Dd;
#pragma unroll
    for (int m = 0; m < 4; ++m) {
#pragma unroll
        for (int i = 0; i < 4; ++i) {
            const int rl = m * 16 + lq * 4 + i;
            const float inv = 1.0f / (lsum[0][rl] + lsum[1][rl]);
#pragma unroll
            for (int nt = 0; nt < 4; ++nt)
                Ob[(size_t)rl * Dd + d * 64 + nt * 16 + lr] = o[m][nt][i] * inv;
        }
    }
}

// ---------------- launch ----------------
extern "C" void kernel_launch(void* const* d_in, const int* in_sizes, int n_in,
                              void* d_out, int out_size, void* d_ws, size_t ws_size,
                              hipStream_t stream) {
    const float* x  = (const float*)d_in[0];
    const float* Wq = (const float*)d_in[1];
    const float* bq = (const float*)d_in[2];
    const float* Wk = (const float*)d_in[3];
    const float* bk = (const float*)d_in[4];
    const float* Wv = (const float*)d_in[5];
    const float* bv = (const float*)d_in[6];

    const size_t NE = (size_t)Bb * Ss * Dd;  // 8.39M elements
    _Float16* xb  = (_Float16*)d_ws;
    _Float16* qw  = xb + NE;
    _Float16* kw  = qw + NE;
    _Float16* vtw = kw + NE;
    _Float16* wt  = vtw + NE;  // 3 * 512*512

    conv_x_kernel<<<dim3((unsigned)(NE / 2048)), 256, 0, stream>>>(x, xb);
    conv_w_kernel<<<dim3(16, 16), 256, 0, stream>>>(Wq, wt);
    conv_w_kernel<<<dim3(16, 16), 256, 0, stream>>>(Wk, wt + Dd * Dd);
    conv_w_kernel<<<dim3(16, 16), 256, 0, stream>>>(Wv, wt + 2 * Dd * Dd);
    proj_kernel<<<dim3(128, 4, 3), 256, 0, stream>>>(xb, wt, bq, bk, bv, qw, kw, vtw);
    attn_kernel<<<dim3(32, 8), 512, 0, stream>>>(qw, kw, vtw, (float*)d_out);
}

// Round 5
// 255.209 us; speedup vs baseline: 3.4905x; 1.0270x over previous
//
#include <hip/hip_runtime.h>
#include <stdint.h>

#define Bb 8
#define Ss 2048
#define Dd 512

typedef _Float16 half8 __attribute__((ext_vector_type(8)));
typedef float floatx4 __attribute__((ext_vector_type(4)));

// ---------------- conversion kernels ----------------
__global__ void conv_x_kernel(const float* __restrict__ x, _Float16* __restrict__ xb) {
    int i = (blockIdx.x * 256 + threadIdx.x) * 8;
    float4 a = *(const float4*)(x + i);
    float4 b = *(const float4*)(x + i + 4);
    half8 h;
    h[0] = (_Float16)a.x; h[1] = (_Float16)a.y; h[2] = (_Float16)a.z; h[3] = (_Float16)a.w;
    h[4] = (_Float16)b.x; h[5] = (_Float16)b.y; h[6] = (_Float16)b.z; h[7] = (_Float16)b.w;
    *(half8*)(xb + i) = h;
}

// transpose + convert one 512x512 weight matrix: Wt[e][d] = W[d][e]
__global__ void conv_w_kernel(const float* __restrict__ W, _Float16* __restrict__ Wt) {
    __shared__ float t[32][33];
    int c0 = blockIdx.x * 32, r0 = blockIdx.y * 32;
    int lx = threadIdx.x & 31, ly = threadIdx.x >> 5;  // ly 0..7
#pragma unroll
    for (int i = 0; i < 32; i += 8)
        t[ly + i][lx] = W[(size_t)(r0 + ly + i) * Dd + c0 + lx];
    __syncthreads();
#pragma unroll
    for (int i = 0; i < 32; i += 8)
        Wt[(size_t)(c0 + ly + i) * Dd + r0 + lx] = (_Float16)t[lx][ly + i];
}

// ---------------- fused QKV projection GEMM ----------------
__device__ __forceinline__ void gl_lds16(const _Float16* g, _Float16* l) {
    __builtin_amdgcn_global_load_lds(
        (__attribute__((address_space(1))) void*)(g),
        (__attribute__((address_space(3))) void*)(l), 16, 0, 0);
}

__launch_bounds__(256)
__global__ void proj_kernel(const _Float16* __restrict__ xb,
                            const _Float16* __restrict__ wt,   // [3][512][512] transposed
                            const float* __restrict__ bq,
                            const float* __restrict__ bk,
                            const float* __restrict__ bv,
                            _Float16* __restrict__ qo,
                            _Float16* __restrict__ ko,
                            _Float16* __restrict__ vto) {
    __shared__ __align__(16) _Float16 At[128 * 32];
    __shared__ __align__(16) _Float16 Bt[128 * 32];
    __shared__ __align__(16) _Float16 R[128 * 136];  // repack tile (stride 136: 16B-aligned rows)
    const int pz = blockIdx.z;
    const _Float16* W = wt + (size_t)pz * Dd * Dd;
    const float* bias = (pz == 0) ? bq : ((pz == 1) ? bk : bv);
    const int tid = threadIdx.x;
    const int wv = tid >> 6, lane = tid & 63;
    const int m0 = blockIdx.x * 128, n0 = blockIdx.y * 128;
    const int li = wv * 2;
    const int srow = lane >> 2;       // 0..15
    const int scol = (lane & 3) * 8;  // 0,8,16,24
    const int wm = (wv & 1) * 64, wn = (wv >> 1) * 64;
    const int lr = lane & 15, lq = lane >> 4;
    floatx4 acc[4][4] = {};
    for (int kk = 0; kk < Dd; kk += 32) {
#pragma unroll
        for (int inst = 0; inst < 2; ++inst) {
            int r = (li + inst) * 16 + srow;
            gl_lds16(xb + (size_t)(m0 + r) * Dd + kk + scol, At + (li + inst) * 512 + lane * 8);
            gl_lds16(W + (size_t)(n0 + r) * Dd + kk + scol, Bt + (li + inst) * 512 + lane * 8);
        }
        __syncthreads();
        half8 af[4], bf[4];
#pragma unroll
        for (int mi = 0; mi < 4; ++mi)
            af[mi] = *(const half8*)&At[(wm + mi * 16 + lr) * 32 + lq * 8];
#pragma unroll
        for (int ni = 0; ni < 4; ++ni)
            bf[ni] = *(const half8*)&Bt[(wn + ni * 16 + lr) * 32 + lq * 8];
#pragma unroll
        for (int mi = 0; mi < 4; ++mi)
#pragma unroll
            for (int ni = 0; ni < 4; ++ni)
                acc[mi][ni] = __builtin_amdgcn_mfma_f32_16x16x32_f16(af[mi], bf[ni], acc[mi][ni], 0, 0, 0);
        __syncthreads();
    }
    // ---- epilogue: bias + repack through LDS, then coalesced half8 stores ----
#pragma unroll
    for (int ni = 0; ni < 4; ++ni) {
        const int gn_l = wn + ni * 16 + lr;
        const float bb = bias[n0 + gn_l];
#pragma unroll
        for (int mi = 0; mi < 4; ++mi) {
#pragma unroll
            for (int rr = 0; rr < 4; ++rr) {
                const int gm_l = wm + mi * 16 + lq * 4 + rr;
                const float v = acc[mi][ni][rr] + bb;
                if (pz == 2) R[gn_l * 136 + gm_l] = (_Float16)v;   // v: transposed layout
                else         R[gm_l * 136 + gn_l] = (_Float16)v;   // q,k: row-major
            }
        }
    }
    __syncthreads();
    const int row = tid >> 1, hf = tid & 1;
    _Float16* dst;
    if (pz == 0)      dst = qo + (size_t)(m0 + row) * Dd + n0 + hf * 64;
    else if (pz == 1) dst = ko + (size_t)(m0 + row) * Dd + n0 + hf * 64;
    else              dst = vto + ((size_t)(m0 >> 11) * Dd + n0 + row) * Ss + (m0 & 2047) + hf * 64;
#pragma unroll
    for (int j = 0; j < 8; ++j)
        *(half8*)(dst + j * 8) = *(const half8*)&R[row * 136 + hf * 64 + j * 8];
}

// ---------------- flash attention: pipelined, swizzled-V, lagged PV ----------------
// Grid (S/64, B), 512 threads = 8 waves, 64 Q-rows/block, key-tile 32, 65 iters.
// Per iter: ONE barrier -> issue DMA stage K(kt+1), V(kt) -> scores(kt) from
// K staged last iter -> PV(kt-1) from P/V written last iter. All DMAs are a
// full compute-phase old at their consuming barrier => vmcnt drain ~free.
// V layout XOR-swizzled: chunk cc = lq ^ (dcol&3) ^ ((dcol>>2)&3) => max
// 2-way bank aliasing (free, m136) on PV B-frag reads (was 8-way).
// LDS: K 2x32x520 + V 2x512x32 + P 2x64x40 + lsum = 142,848 B -> 1 block/CU.
#define KSTR 520   // K row stride (halves): 1040 B = 16-aligned, 4-bank col step
#define PSTR 40    // P row stride (halves)
__launch_bounds__(512, 2)
__global__ void attn_kernel(const _Float16* __restrict__ q,
                            const _Float16* __restrict__ k,
                            const _Float16* __restrict__ vt,
                            float* __restrict__ out) {
    __shared__ __align__(16) _Float16 Klds[2 * 32 * KSTR];
    __shared__ __align__(16) _Float16 Vlds[2 * 512 * 32];
    __shared__ __align__(16) _Float16 P[2 * 64 * PSTR];
    __shared__ float lsum[2][64];
    const int b = blockIdx.y;
    const int tid = threadIdx.x;
    const int wv = tid >> 6, lane = tid & 63;
    const int lr = lane & 15, lq = lane >> 4;
    const int r = wv >> 1, c = wv & 1;   // score roles: 4 row-groups x 2 col-groups(16)
    const int d = wv;                    // PV role: 8 D-col groups of 64
    const int qrow0 = blockIdx.x * 64;
    const _Float16* Qb = q + (size_t)b * Ss * Dd;
    const _Float16* Kb = k + (size_t)b * Ss * Dd;
    const _Float16* Vb = vt + (size_t)b * Dd * Ss;

    // Q fragments: 16 rows, kernel-resident (64 VGPR)
    half8 qf[16];
#pragma unroll
    for (int s = 0; s < 16; ++s)
        qf[s] = *(const half8*)&Qb[(size_t)(qrow0 + r * 16 + lr) * Dd + s * 32 + lq * 8];

    // staging pointers
    // K: wave stages 4 rows (wv*4+j), one inst = one full row (64 lanes x 16B = 1KB)
    const _Float16* kbase = Kb + (size_t)(wv * 4) * Dd + lane * 8;
    // V: wave stages dcols [wv*64, wv*64+64), lane ll -> local row ll>>2, phys chunk ll&3,
    // logical chunk kl = (ll&3)^((ll>>2)&3)^((ll>>4)&3)  (j-independent)
    const int kl = (lane & 3) ^ ((lane >> 2) & 3) ^ ((lane >> 4) & 3);
    const _Float16* vbase = Vb + (size_t)(wv * 64 + (lane >> 2)) * Ss + kl * 8;
    const int vsw = lq ^ (lr & 3) ^ ((lr >> 2) & 3);  // PV read-side swizzle (lane-only)

    floatx4 o[4][4] = {};
    float lp[4] = {0.f, 0.f, 0.f, 0.f};
    const float c1 = 0.044194173824159216f * 1.4426950408889634f;  // (1/sqrt(512))*log2(e)
    const float c2 = 12.0f * 1.4426950408889634f;                  // static shift

    // prologue: stage K tile 0 into buffer 0
#pragma unroll
    for (int j = 0; j < 4; ++j)
        gl_lds16(kbase + (size_t)j * Dd, Klds + (wv * 4 + j) * KSTR + lane * 8);

    for (int kt = 0; kt <= 64; ++kt) {
        const int cur = kt & 1, prv = cur ^ 1;
        __syncthreads();  // DMAs consumed here are a full iteration old

        if (kt < 64) {
            // ---- issue async staging: K for kt+1, V for kt ----
            if (kt < 63) {
                const _Float16* ks = kbase + (size_t)(kt + 1) * 32 * Dd;
                _Float16* kd = Klds + prv * (32 * KSTR) + wv * 4 * KSTR + lane * 8;
#pragma unroll
                for (int j = 0; j < 4; ++j)
                    gl_lds16(ks + (size_t)j * Dd, kd + j * KSTR);
            }
            {
                const _Float16* vs = vbase + kt * 32;
                _Float16* vd = Vlds + cur * (512 * 32) + wv * 2048 + lane * 8;
#pragma unroll
                for (int j = 0; j < 4; ++j)
                    gl_lds16(vs + (size_t)j * 16 * Ss, vd + j * 512);
            }
            // ---- scores(kt): 16 rows x 16 cols per wave from K[cur] ----
            floatx4 s[2] = {};
            const _Float16* Kc = Klds + cur * (32 * KSTR) + (c * 16 + lr) * KSTR + lq * 8;
#pragma unroll
            for (int kk = 0; kk < 16; ++kk) {
                half8 kf = *(const half8*)(Kc + kk * 32);
                s[kk & 1] = __builtin_amdgcn_mfma_f32_16x16x32_f16(qf[kk], kf, s[kk & 1], 0, 0, 0);
            }
            _Float16* Pc = P + cur * (64 * PSTR);
#pragma unroll
            for (int i = 0; i < 4; ++i) {
                float p = __builtin_amdgcn_exp2f((s[0][i] + s[1][i]) * c1 - c2);
                lp[i] += p;
                Pc[(r * 16 + lq * 4 + i) * PSTR + c * 16 + lr] = (_Float16)p;
            }
        }
        if (kt > 0) {
            // ---- PV(kt-1): o(64 rows x wave's 64 D-cols) += P[prv] * V[prv] ----
            const _Float16* Pp = P + prv * (64 * PSTR);
            const _Float16* Vp = Vlds + prv * (512 * 32);
            half8 af[4];
#pragma unroll
            for (int m = 0; m < 4; ++m)
                af[m] = *(const half8*)&Pp[(m * 16 + lr) * PSTR + lq * 8];
#pragma unroll
            for (int nt = 0; nt < 4; ++nt) {
                half8 vf = *(const half8*)&Vp[(d * 64 + nt * 16 + lr) * 32 + vsw * 8];
#pragma unroll
                for (int m = 0; m < 4; ++m)
                    o[m][nt] = __builtin_amdgcn_mfma_f32_16x16x32_f16(af[m], vf, o[m][nt], 0, 0, 0);
            }
        }
    }

    // ---- row-sum combine across the two col-groups ----
#pragma unroll
    for (int i = 0; i < 4; ++i) {
#pragma unroll
        for (int m = 1; m < 16; m <<= 1)
            lp[i] += __shfl_xor(lp[i], m);
    }
    if (lr == 0) {
#pragma unroll
        for (int i = 0; i < 4; ++i)
            lsum[c][r * 16 + lq * 4 + i] = lp[i];
    }
    __syncthreads();

    // ---- epilogue: wave d writes its 64 D-cols for all 64 rows ----
    float* Ob = out + ((size_t)b * Ss + qrow0) * Dd;
#pragma unroll
    for (int m = 0; m < 4; ++m) {
#pragma unroll
        for (int i = 0; i < 4; ++i) {
            const int rl = m * 16 + lq * 4 + i;
            const float inv = 1.0f / (lsum[0][rl] + lsum[1][rl]);
#pragma unroll
            for (int nt = 0; nt < 4; ++nt)
                Ob[(size_t)rl * Dd + d * 64 + nt * 16 + lr] = o[m][nt][i] * inv;
        }
    }
}

// ---------------- launch ----------------
extern "C" void kernel_launch(void* const* d_in, const int* in_sizes, int n_in,
                              void* d_out, int out_size, void* d_ws, size_t ws_size,
                              hipStream_t stream) {
    const float* x  = (const float*)d_in[0];
    const float* Wq = (const float*)d_in[1];
    const float* bq = (const float*)d_in[2];
    const float* Wk = (const float*)d_in[3];
    const float* bk = (const float*)d_in[4];
    const float* Wv = (const float*)d_in[5];
    const float* bv = (const float*)d_in[6];

    const size_t NE = (size_t)Bb * Ss * Dd;  // 8.39M elements
    _Float16* xb  = (_Float16*)d_ws;
    _Float16* qw  = xb + NE;
    _Float16* kw  = qw + NE;
    _Float16* vtw = kw + NE;
    _Float16* wt  = vtw + NE;  // 3 * 512*512

    conv_x_kernel<<<dim3((unsigned)(NE / 2048)), 256, 0, stream>>>(x, xb);
    conv_w_kernel<<<dim3(16, 16), 256, 0, stream>>>(Wq, wt);
    conv_w_kernel<<<dim3(16, 16), 256, 0, stream>>>(Wk, wt + Dd * Dd);
    conv_w_kernel<<<dim3(16, 16), 256, 0, stream>>>(Wv, wt + 2 * Dd * Dd);
    proj_kernel<<<dim3(128, 4, 3), 256, 0, stream>>>(xb, wt, bq, bk, bv, qw, kw, vtw);
    attn_kernel<<<dim3(32, 8), 512, 0, stream>>>(qw, kw, vtw, (float*)d_out);
}